// Round 4
// baseline (322.944 us; speedup 1.0000x reference)
//
#include <hip/hip_runtime.h>

// SNN: B=4096, T=784, H=128, OUT=10.  1 wave/block, 4 batches/wave,
// 16 lanes/batch, 8 h/lane.  Software-pipelined: phase B (layer-2 reduce+LIF2)
// for step t-1 runs under phase A (LIF1 + s1*W2 partials) of step t, with
// double-buffered LDS partials (static parity via the x-float4 unroll).
// Single-wave block: DS pipe is in-order per wave -> no __syncthreads.

#define T_STEPS 784
#define T4      196
#define HID     128
#define NOUT    10
#define TSTART  522   // T*2//3

__global__ __launch_bounds__(64, 1)
void snn_kernel(const float* __restrict__ x,    // [B, T]
                const float* __restrict__ W1,   // [H]
                const float* __restrict__ b1,   // [H]
                const float* __restrict__ W2,   // [OUT, H]
                const float* __restrict__ b2,   // [OUT]
                float* __restrict__ out)        // [B, OUT]
{
    __shared__ float buf0[64 * 13];   // 13-pad: 2-way bank alias only (free)
    __shared__ float buf1[64 * 13];

    const int tid   = threadIdx.x;
    const int l16   = tid & 15;
    const int batch = blockIdx.x * 4 + (tid >> 4);
    const int h0    = l16 * 8;

    // ---- weights in registers ----
    float w1v[8], b1v[8], w2v[NOUT][8];
#pragma unroll
    for (int j = 0; j < 8; ++j) { w1v[j] = W1[h0 + j]; b1v[j] = b1[h0 + j]; }
#pragma unroll
    for (int o = 0; o < NOUT; ++o)
#pragma unroll
        for (int j = 0; j < 8; ++j) w2v[o][j] = W2[o * HID + h0 + j];

    float v1[8];
#pragma unroll
    for (int j = 0; j < 8; ++j) v1[j] = 0.0f;

    // ---- phase-B lane role: lane = bb*10 + ob, lanes 0..39 ----
    const bool bact = (tid < 40);
    const int  bb   = tid / 10;
    const int  ob   = tid - bb * 10;
    float b2v = bact ? b2[ob] : 0.0f;
    float v2 = 0.0f, outacc = 0.0f;

    float* const wb0 = &buf0[tid * 13];
    float* const wb1 = &buf1[tid * 13];
    const float* const rb0 = &buf0[bb * 16 * 13 + ob];   // + k*13
    const float* const rb1 = &buf1[bb * 16 * 13 + ob];

    // ---- phase A: LIF1 + partial dot, write partials to wb ----
    auto phaseA = [&](float xv, float* wb) {
        float acc[NOUT];
        {
            float h1 = fmaf(xv, w1v[0], b1v[0]);
            float d  = h1 - v1[0];
            float vn = fmaf(d, 0.5f, v1[0]);
            bool  s  = (vn >= 1.0f);
            float sf = s ? 1.0f : 0.0f;
            v1[0]    = s ? 0.0f : vn;
#pragma unroll
            for (int o = 0; o < NOUT; ++o) acc[o] = sf * w2v[o][0];
        }
#pragma unroll
        for (int j = 1; j < 8; ++j) {
            float h1 = fmaf(xv, w1v[j], b1v[j]);
            float d  = h1 - v1[j];
            float vn = fmaf(d, 0.5f, v1[j]);
            bool  s  = (vn >= 1.0f);
            float sf = s ? 1.0f : 0.0f;
            v1[j]    = s ? 0.0f : vn;
#pragma unroll
            for (int o = 0; o < NOUT; ++o) acc[o] = fmaf(sf, w2v[o][j], acc[o]);
        }
#pragma unroll
        for (int o = 0; o < NOUT; ++o) wb[o] = acc[o];
    };

    // ---- phase B issue: read 16 partials for this lane's (batch,out) ----
    auto readP = [&](const float* rb, float* p) {
#pragma unroll
        for (int k = 0; k < 16; ++k) p[k] = rb[k * 13];
    };
    // ---- phase B finish: reduce + LIF2 + spike count ----
    auto finishB = [&](const float* p, int sPrev) {
        if (bact) {
            float s0 = ((p[0] + p[1]) + (p[2] + p[3])) + ((p[4] + p[5]) + (p[6] + p[7]));
            float s1 = ((p[8] + p[9]) + (p[10] + p[11])) + ((p[12] + p[13]) + (p[14] + p[15]));
            float h2  = (s0 + s1) + b2v;
            float d2  = h2 - v2;
            float v2n = fmaf(d2, 0.5f, v2);
            bool  sp  = (v2n >= 1.0f);
            v2 = sp ? 0.0f : v2n;
            outacc += (sp && sPrev >= TSTART) ? 1.0f : 0.0f;
        }
    };

    const float4* xrow = reinterpret_cast<const float4*>(x + (size_t)batch * T_STEPS);
    float4 xc = xrow[0];

    // ---- peeled t4 = 0 (fills the pipeline) ----
    {
        float4 xn = xrow[1];
        float p[16];
        phaseA(xc.x, wb0);                                   // s=0 -> buf0
        readP(rb0, p); phaseA(xc.y, wb1); finishB(p, 0);     // s=1 -> buf1, B(0)
        readP(rb1, p); phaseA(xc.z, wb0); finishB(p, 1);     // s=2 -> buf0, B(1)
        readP(rb0, p); phaseA(xc.w, wb1); finishB(p, 2);     // s=3 -> buf1, B(2)
        xc = xn;
    }

    // ---- steady loop: t4 = 1..195; step s = 4*t4+u, phase B runs for s-1 ----
    for (int t4 = 1; t4 < T4; ++t4) {
        float4 xn = xrow[(t4 + 1 < T4) ? (t4 + 1) : t4];     // uniform clamp (scalar)
        const int s0i = t4 * 4;
        float p[16];
        readP(rb1, p); phaseA(xc.x, wb0); finishB(p, s0i - 1);  // s even -> buf0
        readP(rb0, p); phaseA(xc.y, wb1); finishB(p, s0i);      // s odd  -> buf1
        readP(rb1, p); phaseA(xc.z, wb0); finishB(p, s0i + 1);
        readP(rb0, p); phaseA(xc.w, wb1); finishB(p, s0i + 2);
        xc = xn;
    }

    // ---- drain: phase B for s = 783 (parity 1) ----
    {
        float p[16];
        readP(rb1, p);
        finishB(p, 783);
    }

    if (bact) out[blockIdx.x * 40 + tid] = outacc;   // = out[(blk*4+bb)*10 + ob]
}

extern "C" void kernel_launch(void* const* d_in, const int* in_sizes, int n_in,
                              void* d_out, int out_size, void* d_ws, size_t ws_size,
                              hipStream_t stream)
{
    const float* x  = (const float*)d_in[0];
    const float* W1 = (const float*)d_in[1];
    const float* b1 = (const float*)d_in[2];
    const float* W2 = (const float*)d_in[3];
    const float* b2 = (const float*)d_in[4];
    float* out = (float*)d_out;

    snn_kernel<<<dim3(1024), dim3(64), 0, stream>>>(x, W1, b1, W2, b2, out);
}